// Round 2
// baseline (1330.932 us; speedup 1.0000x reference)
//
#include <hip/hip_runtime.h>
#include <hip/hip_bf16.h>

typedef __hip_bfloat16 bf16;

#define NB 16

// drug conv chain:  L 64 ->61(K4,C40) ->56(K6,C80) ->49(K8,C160)
// prot conv chain:  L 1200 ->1197(K4,C40) ->1190(K8,C80) ->1179(K12,C160)

__device__ __forceinline__ float b2f(bf16 x) { return __bfloat162float(x); }
__device__ __forceinline__ float u16bf(unsigned short u) {
    return __uint_as_float(((unsigned)u) << 16);
}

// ---------------- dtype sniffer ----------------
// Examines even-indexed u16 halves of fc2W (1,048,576 elems). If the buffer is
// bf16, those are real N(0,0.05) values (|v| in (1e-6,2) ~always). If it is
// f32, they are low-mantissa junk (~8% pass). flag=1 -> bf16 inputs.
__global__ void sniff_kernel(const unsigned short* __restrict__ w, int* __restrict__ flag) {
    __shared__ int cnt;
    if (threadIdx.x == 0) cnt = 0;
    __syncthreads();
    int hits = 0;
    for (int s = 0; s < 4; s++) {
        unsigned short u = w[(threadIdx.x * 4 + s) * 2];
        float v = fabsf(u16bf(u));
        if (v > 1e-6f && v < 2.0f) hits++;
    }
    atomicAdd(&cnt, hits);
    __syncthreads();
    if (threadIdx.x == 0) *flag = (cnt > 512) ? 1 : 0;   // of 1024 samples
}

// ---------------- conversions (flag-aware) ----------------
#define NSEG 21
struct CvtJob {
    const void* src[NSEG];
    float* dst[NSEG];
    int n[NSEG];
};

__global__ void megacvt(CvtJob job, const int* __restrict__ flagp) {
    int seg = blockIdx.y;
    int i = blockIdx.x * 256 + threadIdx.x;
    if (i >= job.n[seg]) return;
    float v = (*flagp) ? b2f(((const bf16*)job.src[seg])[i])
                       : ((const float*)job.src[seg])[i];
    job.dst[seg][i] = v;
}

// [160,160] (o,c) -> f32 transposed [c*160+o], three matrices in one launch
__global__ void cvt160t(const void* s0, const void* s1, const void* s2,
                        float* d0, float* d1, float* d2, const int* __restrict__ flagp) {
    int i = blockIdx.x * 256 + threadIdx.x;
    if (i >= 25600) return;
    const void* s = blockIdx.y == 0 ? s0 : (blockIdx.y == 1 ? s1 : s2);
    float* d = blockIdx.y == 0 ? d0 : (blockIdx.y == 1 ? d1 : d2);
    int o = i / 160, c = i % 160;
    float v = (*flagp) ? b2f(((const bf16*)s)[i]) : ((const float*)s)[i];
    d[c * 160 + o] = v;
}

__global__ void pair_init(float* __restrict__ pair) {
    int i = blockIdx.x * 256 + threadIdx.x;
    if (i < NB * 320) pair[i] = 0.f;
}

// ---------------- conv1 fused with embedding gather ----------------
// CIN=64, K=4, Cout=40. grid (B*tilesL, 5), block 256.
__global__ void conv1_embed(const int* __restrict__ tok, const float* __restrict__ embF,
                            const float* __restrict__ w, const float* __restrict__ bias,
                            bf16* __restrict__ y, int Lin, int Lout) {
    const int K = 4, CIN = 64, TLX = 67;
    __shared__ float xs[CIN * TLX];
    __shared__ int stok[TLX];
    int tilesL = (Lout + 63) >> 6;
    int b = blockIdx.x / tilesL;
    int l0 = (blockIdx.x % tilesL) << 6;
    if (threadIdx.x < TLX) {
        int l = l0 + threadIdx.x;
        stok[threadIdx.x] = (l < Lin) ? tok[b * Lin + l] : -1;
    }
    __syncthreads();
    for (int i = threadIdx.x; i < CIN * TLX; i += 256) {
        int ci = i / TLX, j = i % TLX;
        int t = stok[j];
        xs[i] = (t >= 0) ? embF[t * 64 + ci] : 0.f;
    }
    __syncthreads();
    int li = threadIdx.x & 63, cg = threadIdx.x >> 6;
    int l = l0 + li;
    int co0 = blockIdx.y * 8 + cg, co1 = co0 + 4;
    float acc0 = bias[co0], acc1 = bias[co1];
    const float* w0 = w + co0 * CIN * K;
    const float* w1 = w + co1 * CIN * K;
    for (int ci = 0; ci < CIN; ci++) {
        const float* xr = xs + ci * TLX + li;
#pragma unroll
        for (int k = 0; k < K; k++) {
            acc0 += xr[k] * w0[ci * K + k];
            acc1 += xr[k] * w1[ci * K + k];
        }
    }
    if (l < Lout) {
        y[((size_t)b * 40 + co0) * Lout + l] = __float2bfloat16(fmaxf(acc0, 0.f));
        y[((size_t)b * 40 + co1) * Lout + l] = __float2bfloat16(fmaxf(acc1, 0.f));
    }
}

// ---------------- conv (bf16 activations, f32 weights) ----------------
// grid (B*tilesL, Cout/8), block 256. 2 output channels per thread.
template <int CIN, int K>
__global__ void conv_bf16(const bf16* __restrict__ x, const float* __restrict__ w,
                          const float* __restrict__ bias, bf16* __restrict__ y,
                          int Lin, int Lout, int Cout) {
    const int TLX = 64 + K - 1;
    __shared__ float xs[CIN * TLX];
    int tilesL = (Lout + 63) >> 6;
    int b = blockIdx.x / tilesL;
    int l0 = (blockIdx.x % tilesL) << 6;
    const bf16* xb = x + (size_t)b * CIN * Lin;
    for (int i = threadIdx.x; i < CIN * TLX; i += 256) {
        int ci = i / TLX, j = i % TLX;
        int l = l0 + j;
        xs[i] = (l < Lin) ? b2f(xb[ci * Lin + l]) : 0.f;
    }
    __syncthreads();
    int li = threadIdx.x & 63, cg = threadIdx.x >> 6;
    int l = l0 + li;
    int co0 = blockIdx.y * 8 + cg, co1 = co0 + 4;
    float acc0 = bias[co0], acc1 = bias[co1];
    const float* w0 = w + (size_t)co0 * CIN * K;
    const float* w1 = w + (size_t)co1 * CIN * K;
    for (int ci = 0; ci < CIN; ci++) {
        const float* xr = xs + ci * TLX + li;
#pragma unroll
        for (int k = 0; k < K; k++) {
            float xv = xr[k];
            acc0 += xv * w0[ci * K + k];
            acc1 += xv * w1[ci * K + k];
        }
    }
    if (l < Lout) {
        y[((size_t)b * Cout + co0) * Lout + l] = __float2bfloat16(fmaxf(acc0, 0.f));
        y[((size_t)b * Cout + co1) * Lout + l] = __float2bfloat16(fmaxf(acc1, 0.f));
    }
}

// ---------------- attention projection ----------------
// y[b,l,o] = sum_c x[b,c,l] * W[o,c] + bias[o]; wt transposed [c*160+o].
// grid (B*tilesL, 4), block 256.
__device__ __forceinline__ void stv(float* p, float v) { *p = v; }
__device__ __forceinline__ void stv(bf16* p, float v) { *p = __float2bfloat16(v); }

template <typename OT>
__global__ void att_proj(const bf16* __restrict__ x, const float* __restrict__ wt,
                         const float* __restrict__ bias, OT* __restrict__ y, int L) {
    __shared__ float xs[160 * 64];
    int tilesL = (L + 63) >> 6;
    int b = blockIdx.x / tilesL;
    int l0 = (blockIdx.x % tilesL) << 6;
    const bf16* xb = x + (size_t)b * 160 * L;
    for (int i = threadIdx.x; i < 160 * 64; i += 256) {
        int c = i >> 6, j = i & 63;
        int l = l0 + j;
        xs[i] = (l < L) ? b2f(xb[c * L + l]) : 0.f;
    }
    __syncthreads();
    int li = threadIdx.x & 63, og = threadIdx.x >> 6;
    int o0 = blockIdx.y * 40 + og * 10;
    float acc[10];
#pragma unroll
    for (int j = 0; j < 10; j++) acc[j] = bias[o0 + j];
    for (int c = 0; c < 160; c++) {
        float xv = xs[(c << 6) + li];
        const float* wr = wt + c * 160 + o0;
#pragma unroll
        for (int j = 0; j < 10; j++) acc[j] += xv * wr[j];
    }
    int l = l0 + li;
    if (l < L) {
        OT* yr = y + ((size_t)b * L + l) * 160 + o0;
#pragma unroll
        for (int j = 0; j < 10; j++) stv(yr + j, acc[j]);
    }
}

// ---------------- drug side: mean over p, attW matmul, sigmoid, scale, max ----------------
// grid B*7 (7 d-rows per block), block 192 (160 active).
__global__ void drug_fuse(const float* __restrict__ datt, const bf16* __restrict__ patt,
                          const bf16* __restrict__ dcB, const float* __restrict__ wattT,
                          const float* __restrict__ attbF, float* __restrict__ pair) {
    __shared__ float sMd[7 * 160];
    int b = blockIdx.x / 7;
    int dg = blockIdx.x % 7;
    int k = threadIdx.x;
    if (k < 160) {
        float dv[7], acc[7];
#pragma unroll
        for (int t = 0; t < 7; t++) {
            dv[t] = datt[((size_t)b * 49 + dg * 7 + t) * 160 + k];
            acc[t] = 0.f;
        }
        const bf16* pb = patt + (size_t)b * 1179 * 160 + k;
        for (int p = 0; p < 1179; p++) {
            float pv = b2f(pb[(size_t)p * 160]);
#pragma unroll
            for (int t = 0; t < 7; t++) acc[t] += fmaxf(dv[t] + pv, 0.f);
        }
#pragma unroll
        for (int t = 0; t < 7; t++) sMd[t * 160 + k] = acc[t] * (1.f / 1179.f);
    }
    __syncthreads();
    if (k < 160) {
        float localmax = 0.f;
        for (int t = 0; t < 7; t++) {
            float a = attbF[k];
            for (int kk = 0; kk < 160; kk++) a += sMd[t * 160 + kk] * wattT[kk * 160 + k];
            float sig = 1.f / (1.f + expf(-a));
            int d = dg * 7 + t;
            float val = b2f(dcB[((size_t)b * 160 + k) * 49 + d]) * (0.5f + sig);
            localmax = fmaxf(localmax, val);
        }
        atomicMax((unsigned int*)(pair + b * 320 + k), __float_as_uint(localmax));
    }
}

// ---------------- protein side ----------------
// grid B*148 (8 p-rows per block), block 192 (160 active).
#define PR 8
__global__ void prot_fuse(const float* __restrict__ datt, const bf16* __restrict__ patt,
                          const bf16* __restrict__ pcB, const float* __restrict__ wattT,
                          const float* __restrict__ attbF, float* __restrict__ pair) {
    __shared__ float sdatt[49 * 160];
    __shared__ float ss[160];
    int tiles = (1179 + PR - 1) / PR;   // 148
    int b = blockIdx.x / tiles;
    int p0 = (blockIdx.x % tiles) * PR;
    for (int i = threadIdx.x; i < 49 * 160; i += 192)
        sdatt[i] = datt[(size_t)b * 49 * 160 + i];
    __syncthreads();
    int k = threadIdx.x;
    float localmax = 0.f;
    int pend = min(p0 + PR, 1179);
    for (int p = p0; p < pend; p++) {
        if (k < 160) {
            float pv = b2f(patt[((size_t)b * 1179 + p) * 160 + k]);
            float s = 0.f;
            for (int d = 0; d < 49; d++) s += fmaxf(sdatt[d * 160 + k] + pv, 0.f);
            ss[k] = s * (1.f / 49.f);
        }
        __syncthreads();
        if (k < 160) {
            float a = attbF[k];
            for (int kk = 0; kk < 160; kk++) a += ss[kk] * wattT[kk * 160 + k];
            float sig = 1.f / (1.f + expf(-a));
            float val = b2f(pcB[((size_t)b * 160 + k) * 1179 + p]) * (0.5f + sig);
            localmax = fmaxf(localmax, val);
        }
        __syncthreads();
    }
    if (k < 160) atomicMax((unsigned int*)(pair + b * 320 + 160 + k), __float_as_uint(localmax));
}

// ---------------- MLP head ----------------
__global__ void lin_leaky(const float* __restrict__ in, const void* __restrict__ W,
                          const float* __restrict__ bias, float* __restrict__ out,
                          int IN, int OUT, const int* __restrict__ flagp) {
    int idx = blockIdx.x * 256 + threadIdx.x;
    if (idx >= NB * OUT) return;
    int b = idx / OUT, j = idx % OUT;
    const float* ir = in + (size_t)b * IN;
    float acc = bias[j];
    if (*flagp) {
        const bf16* wr = (const bf16*)W + (size_t)j * IN;
        for (int i = 0; i < IN; i++) acc += ir[i] * b2f(wr[i]);
    } else {
        const float* wr = (const float*)W + (size_t)j * IN;
        for (int i = 0; i < IN; i++) acc += ir[i] * wr[i];
    }
    out[idx] = acc > 0.f ? acc : 0.01f * acc;
}

__global__ void out_layer(const float* __restrict__ h, const void* __restrict__ W,
                          const float* __restrict__ biasF, void* __restrict__ out,
                          const int* __restrict__ flagp) {
    int idx = threadIdx.x;
    if (idx >= 32) return;
    int b = idx >> 1, o = idx & 1;
    float acc = biasF[o];
    const float* ir = h + b * 512;
    if (*flagp) {
        const bf16* wr = (const bf16*)W + o * 512;
        for (int i = 0; i < 512; i++) acc += ir[i] * b2f(wr[i]);
        ((bf16*)out)[idx] = __float2bfloat16(acc);
    } else {
        const float* wr = (const float*)W + o * 512;
        for (int i = 0; i < 512; i++) acc += ir[i] * wr[i];
        ((float*)out)[idx] = acc;
    }
}

extern "C" void kernel_launch(void* const* d_in, const int* in_sizes, int n_in,
                              void* d_out, int out_size, void* d_ws, size_t ws_size,
                              hipStream_t stream) {
    const int* drug_tok = (const int*)d_in[0];
    const int* prot_tok = (const int*)d_in[1];
    // raw (dtype decided at runtime by sniffer):
    const void* drug_emb = d_in[2];
    const void* prot_emb = d_in[3];
    const void* dW1 = d_in[4];  const void* db1 = d_in[5];
    const void* dW2 = d_in[6];  const void* db2 = d_in[7];
    const void* dW3 = d_in[8];  const void* db3 = d_in[9];
    const void* pW1 = d_in[10]; const void* pb1 = d_in[11];
    const void* pW2 = d_in[12]; const void* pb2 = d_in[13];
    const void* pW3 = d_in[14]; const void* pb3 = d_in[15];
    const void* dattW = d_in[16]; const void* dattb = d_in[17];
    const void* pattW = d_in[18]; const void* pattb = d_in[19];
    const void* attW  = d_in[20]; const void* attb  = d_in[21];
    const void* fc1W = d_in[22]; const void* fc1b = d_in[23];
    const void* fc2W = d_in[24]; const void* fc2b = d_in[25];
    const void* fc3W = d_in[26]; const void* fc3b = d_in[27];
    const void* outW = d_in[28]; const void* outb = d_in[29];

    // ---- workspace layout (byte cursor, 256B aligned; ~20 MB total) ----
    char* base = (char*)d_ws;
    size_t cur = 0;
    auto alloc = [&](size_t bytes) -> char* {
        char* p = base + cur;
        cur = (cur + bytes + 255) & ~(size_t)255;
        return p;
    };
    int*   flag  = (int*)alloc(256);
    float* embDF = (float*)alloc(65 * 64 * 4);
    float* embPF = (float*)alloc(26 * 64 * 4);
    float* dW1f = (float*)alloc(10240 * 4);
    float* dW2f = (float*)alloc(19200 * 4);
    float* dW3f = (float*)alloc(102400 * 4);
    float* pW1f = (float*)alloc(10240 * 4);
    float* pW2f = (float*)alloc(25600 * 4);
    float* pW3f = (float*)alloc(153600 * 4);
    float* db1f = (float*)alloc(40 * 4);
    float* db2f = (float*)alloc(80 * 4);
    float* db3f = (float*)alloc(160 * 4);
    float* pb1f = (float*)alloc(40 * 4);
    float* pb2f = (float*)alloc(80 * 4);
    float* pb3f = (float*)alloc(160 * 4);
    float* dattbF = (float*)alloc(160 * 4);
    float* pattbF = (float*)alloc(160 * 4);
    float* attbF  = (float*)alloc(160 * 4);
    float* fc1bF = (float*)alloc(1024 * 4);
    float* fc2bF = (float*)alloc(1024 * 4);
    float* fc3bF = (float*)alloc(512 * 4);
    float* outbF = (float*)alloc(2 * 4);
    float* dattT = (float*)alloc(25600 * 4);
    float* pattT = (float*)alloc(25600 * 4);
    float* wattT = (float*)alloc(25600 * 4);
    bf16* d1  = (bf16*)alloc((size_t)NB * 40 * 61 * 2);
    bf16* d2  = (bf16*)alloc((size_t)NB * 80 * 56 * 2);
    bf16* dcB = (bf16*)alloc((size_t)NB * 160 * 49 * 2);
    bf16* p1  = (bf16*)alloc((size_t)NB * 40 * 1197 * 2);
    bf16* p2  = (bf16*)alloc((size_t)NB * 80 * 1190 * 2);
    bf16* pcB = (bf16*)alloc((size_t)NB * 160 * 1179 * 2);
    float* datt  = (float*)alloc((size_t)NB * 49 * 160 * 4);
    bf16* pattB = (bf16*)alloc((size_t)NB * 1179 * 160 * 2);
    float* pair = (float*)alloc(NB * 320 * 4);
    float* h1 = (float*)alloc(NB * 1024 * 4);
    float* h2 = (float*)alloc(NB * 1024 * 4);
    float* h3 = (float*)alloc(NB * 512 * 4);

    // 1) dtype sniff
    sniff_kernel<<<1, 256, 0, stream>>>((const unsigned short*)fc2W, flag);

    // 2) convert small params to f32
    CvtJob job;
    int si = 0;
    auto add = [&](const void* s, float* d, int n) { job.src[si] = s; job.dst[si] = d; job.n[si] = n; si++; };
    add(dW1, dW1f, 10240); add(dW2, dW2f, 19200); add(dW3, dW3f, 102400);
    add(pW1, pW1f, 10240); add(pW2, pW2f, 25600); add(pW3, pW3f, 153600);
    add(db1, db1f, 40); add(db2, db2f, 80); add(db3, db3f, 160);
    add(pb1, pb1f, 40); add(pb2, pb2f, 80); add(pb3, pb3f, 160);
    add(dattb, dattbF, 160); add(pattb, pattbF, 160); add(attb, attbF, 160);
    add(fc1b, fc1bF, 1024); add(fc2b, fc2bF, 1024); add(fc3b, fc3bF, 512);
    add(outb, outbF, 2);
    add(drug_emb, embDF, 65 * 64); add(prot_emb, embPF, 26 * 64);
    megacvt<<<dim3(600, NSEG), 256, 0, stream>>>(job, flag);
    cvt160t<<<dim3(100, 3), 256, 0, stream>>>(dattW, pattW, attW, dattT, pattT, wattT, flag);
    pair_init<<<(NB * 320 + 255) / 256, 256, 0, stream>>>(pair);

    // 3) CNN stacks (bf16 activations, f32 accumulation)
    conv1_embed<<<dim3(NB * 1, 5), 256, 0, stream>>>(drug_tok, embDF, dW1f, db1f, d1, 64, 61);
    conv1_embed<<<dim3(NB * 19, 5), 256, 0, stream>>>(prot_tok, embPF, pW1f, pb1f, p1, 1200, 1197);
    conv_bf16<40, 6><<<dim3(NB * 1, 10), 256, 0, stream>>>(d1, dW2f, db2f, d2, 61, 56, 80);
    conv_bf16<40, 8><<<dim3(NB * 19, 10), 256, 0, stream>>>(p1, pW2f, pb2f, p2, 1197, 1190, 80);
    conv_bf16<80, 8><<<dim3(NB * 1, 20), 256, 0, stream>>>(d2, dW3f, db3f, dcB, 56, 49, 160);
    conv_bf16<80, 12><<<dim3(NB * 19, 20), 256, 0, stream>>>(p2, pW3f, pb3f, pcB, 1190, 1179, 160);

    // 4) attention projections
    att_proj<float><<<dim3(NB * 1, 4), 256, 0, stream>>>(dcB, dattT, dattbF, datt, 49);
    att_proj<bf16><<<dim3(NB * 19, 4), 256, 0, stream>>>(pcB, pattT, pattbF, pattB, 1179);

    // 5) fused mean / attW matmul / sigmoid / scale / maxpool
    drug_fuse<<<NB * 7, 192, 0, stream>>>(datt, pattB, dcB, wattT, attbF, pair);
    prot_fuse<<<NB * 148, 192, 0, stream>>>(datt, pattB, pcB, wattT, attbF, pair);

    // 6) MLP head
    lin_leaky<<<(NB * 1024 + 255) / 256, 256, 0, stream>>>(pair, fc1W, fc1bF, h1, 320, 1024, flag);
    lin_leaky<<<(NB * 1024 + 255) / 256, 256, 0, stream>>>(h1, fc2W, fc2bF, h2, 1024, 1024, flag);
    lin_leaky<<<(NB * 512 + 255) / 256, 256, 0, stream>>>(h2, fc3W, fc3bF, h3, 1024, 512, flag);
    out_layer<<<1, 64, 0, stream>>>(h3, outW, outbF, d_out, flag);
}

// Round 3
// 912.582 us; speedup vs baseline: 1.4584x; 1.4584x over previous
//
#include <hip/hip_runtime.h>
#include <hip/hip_bf16.h>

typedef __hip_bfloat16 bf16;

#define NB 16

// drug conv chain:  L 64 ->61(K4,C40) ->56(K6,C80) ->49(K8,C160)
// prot conv chain:  L 1200 ->1197(K4,C40) ->1190(K8,C80) ->1179(K12,C160)

__device__ __forceinline__ float b2f(bf16 x) { return __bfloat162float(x); }
__device__ __forceinline__ float u16bf(unsigned short u) {
    return __uint_as_float(((unsigned)u) << 16);
}
__device__ __forceinline__ unsigned short f2bu(float v) {
    union { bf16 h; unsigned short u; } cv;
    cv.h = __float2bfloat16(v);
    return cv.u;
}

// ---------------- dtype sniffer (bf16 vs f32 inputs) ----------------
__global__ void sniff_kernel(const unsigned short* __restrict__ w, int* __restrict__ flag) {
    __shared__ int cnt;
    if (threadIdx.x == 0) cnt = 0;
    __syncthreads();
    int hits = 0;
    for (int s = 0; s < 4; s++) {
        unsigned short u = w[(threadIdx.x * 4 + s) * 2];
        float v = fabsf(u16bf(u));
        if (v > 1e-6f && v < 2.0f) hits++;
    }
    atomicAdd(&cnt, hits);
    __syncthreads();
    if (threadIdx.x == 0) *flag = (cnt > 512) ? 1 : 0;
}

// ---------------- conversions ----------------
#define NSEG 15
struct CvtJob {
    const void* src[NSEG];
    float* dst[NSEG];
    int n[NSEG];
};

__global__ void megacvt(CvtJob job, const int* __restrict__ flagp) {
    int seg = blockIdx.y;
    int i = blockIdx.x * 256 + threadIdx.x;
    if (i >= job.n[seg]) return;
    float v = (*flagp) ? b2f(((const bf16*)job.src[seg])[i])
                       : ((const float*)job.src[seg])[i];
    job.dst[seg][i] = v;
}

// conv weights [Cout][CIN][K] -> f32 [ci*K+k][Cout]
__global__ void cvt_wT(const void* __restrict__ src, float* __restrict__ dst,
                       int Cout, int CK, const int* __restrict__ flagp) {
    int i = blockIdx.x * 256 + threadIdx.x;
    if (i >= Cout * CK) return;
    int co = i / CK, r = i - co * CK;
    float v = (*flagp) ? b2f(((const bf16*)src)[i]) : ((const float*)src)[i];
    dst[r * Cout + co] = v;
}

// [160,160] (o,c) -> f32 transposed [c*160+o], three matrices
__global__ void cvt160t(const void* s0, const void* s1, const void* s2,
                        float* d0, float* d1, float* d2, const int* __restrict__ flagp) {
    int i = blockIdx.x * 256 + threadIdx.x;
    if (i >= 25600) return;
    const void* s = blockIdx.y == 0 ? s0 : (blockIdx.y == 1 ? s1 : s2);
    float* d = blockIdx.y == 0 ? d0 : (blockIdx.y == 1 ? d1 : d2);
    int o = i / 160, c = i % 160;
    float v = (*flagp) ? b2f(((const bf16*)s)[i]) : ((const float*)s)[i];
    d[c * 160 + o] = v;
}

__global__ void zero_init(float* __restrict__ pair, float* __restrict__ Md) {
    int i = blockIdx.x * 256 + threadIdx.x;
    if (i < NB * 320) pair[i] = 0.f;
    if (i < NB * 49 * 160) Md[i] = 0.f;
}

// ---------------- conv v2: register-blocked, scalar weights ----------------
// Each thread: 2 positions x CPT channels. K+1 LDS reads feed K*CPT*2 FMAs.
// grid (B*tilesL, Cout/(4*CPT)), block 256. Ltile = 128.
template <int CIN, int K, int CPT>
__global__ __launch_bounds__(256) void conv_v2(const bf16* __restrict__ x,
                                               const float* __restrict__ wT,
                                               const float* __restrict__ bias,
                                               bf16* __restrict__ y,
                                               int Lin, int Lout, int Cout, int tilesL) {
    const int TLX = 128 + K - 1;
    __shared__ float xs[CIN * TLX];
    int b = blockIdx.x / tilesL;
    int l0 = (blockIdx.x % tilesL) << 7;
    const bf16* xb = x + (size_t)b * CIN * Lin;
    {
        int j = threadIdx.x;
        if (j < TLX) {
            int l = l0 + j;
            bool ok = (l < Lin);
            for (int ci = 0; ci < CIN; ci++)
                xs[ci * TLX + j] = ok ? b2f(xb[ci * Lin + l]) : 0.f;
        }
    }
    __syncthreads();
    int li = threadIdx.x & 63;
    int cg = __builtin_amdgcn_readfirstlane(threadIdx.x >> 6);
    int co0 = (blockIdx.y * 4 + cg) * CPT;
    int p0 = li * 2;
    float acc0[CPT], acc1[CPT];
#pragma unroll
    for (int c = 0; c < CPT; c++) { acc0[c] = bias[co0 + c]; acc1[c] = acc0[c]; }
    for (int ci = 0; ci < CIN; ci++) {
        float xv[K + 1];
#pragma unroll
        for (int t = 0; t <= K; t++) xv[t] = xs[ci * TLX + p0 + t];
        const float* wr = wT + (size_t)(ci * K) * Cout + co0;
#pragma unroll
        for (int k = 0; k < K; k++) {
#pragma unroll
            for (int c = 0; c < CPT; c++) {
                float w = wr[k * Cout + c];
                acc0[c] += xv[k] * w;
                acc1[c] += xv[k + 1] * w;
            }
        }
    }
    int l = l0 + p0;
    if (l < Lout) {
        bool two = (l + 1 < Lout);
#pragma unroll
        for (int c = 0; c < CPT; c++) {
            bf16* yr = y + ((size_t)b * Cout + co0 + c) * Lout + l;
            yr[0] = __float2bfloat16(fmaxf(acc0[c], 0.f));
            if (two) yr[1] = __float2bfloat16(fmaxf(acc1[c], 0.f));
        }
    }
}

// conv1 fused with embedding gather (CIN=64, K=4, Cout=40, CPT=10)
__global__ __launch_bounds__(256) void conv1_embed(const int* __restrict__ tok,
                                                   const float* __restrict__ embF,
                                                   const float* __restrict__ wT,
                                                   const float* __restrict__ bias,
                                                   bf16* __restrict__ y,
                                                   int Lin, int Lout, int tilesL) {
    const int K = 4, CIN = 64, TLX = 131, CPT = 10, Cout = 40;
    __shared__ float xs[CIN * TLX];
    __shared__ int stok[TLX];
    int b = blockIdx.x / tilesL;
    int l0 = (blockIdx.x % tilesL) << 7;
    if (threadIdx.x < TLX) {
        int l = l0 + threadIdx.x;
        stok[threadIdx.x] = (l < Lin) ? tok[b * Lin + l] : -1;
    }
    __syncthreads();
    {
        int j = threadIdx.x;
        if (j < TLX) {
            int t = stok[j];
            for (int ci = 0; ci < CIN; ci++)
                xs[ci * TLX + j] = (t >= 0) ? embF[t * 64 + ci] : 0.f;
        }
    }
    __syncthreads();
    int li = threadIdx.x & 63;
    int cg = __builtin_amdgcn_readfirstlane(threadIdx.x >> 6);
    int co0 = cg * CPT;
    int p0 = li * 2;
    float acc0[CPT], acc1[CPT];
#pragma unroll
    for (int c = 0; c < CPT; c++) { acc0[c] = bias[co0 + c]; acc1[c] = acc0[c]; }
    for (int ci = 0; ci < CIN; ci++) {
        float xv[K + 1];
#pragma unroll
        for (int t = 0; t <= K; t++) xv[t] = xs[ci * TLX + p0 + t];
        const float* wr = wT + (size_t)(ci * K) * Cout + co0;
#pragma unroll
        for (int k = 0; k < K; k++) {
#pragma unroll
            for (int c = 0; c < CPT; c++) {
                float w = wr[k * Cout + c];
                acc0[c] += xv[k] * w;
                acc1[c] += xv[k + 1] * w;
            }
        }
    }
    int l = l0 + p0;
    if (l < Lout) {
        bool two = (l + 1 < Lout);
#pragma unroll
        for (int c = 0; c < CPT; c++) {
            bf16* yr = y + ((size_t)b * Cout + co0 + c) * Lout + l;
            yr[0] = __float2bfloat16(fmaxf(acc0[c], 0.f));
            if (two) yr[1] = __float2bfloat16(fmaxf(acc1[c], 0.f));
        }
    }
}

// ---------------- attention projection (as round 2, + scalar weights) ----------------
__device__ __forceinline__ void stv(float* p, float v) { *p = v; }
__device__ __forceinline__ void stv(bf16* p, float v) { *p = __float2bfloat16(v); }

template <typename OT>
__global__ __launch_bounds__(256) void att_proj(const bf16* __restrict__ x,
                                                const float* __restrict__ wt,
                                                const float* __restrict__ bias,
                                                OT* __restrict__ y, int L) {
    __shared__ float xs[160 * 64];
    int tilesL = (L + 63) >> 6;
    int b = blockIdx.x / tilesL;
    int l0 = (blockIdx.x % tilesL) << 6;
    const bf16* xb = x + (size_t)b * 160 * L;
    for (int i = threadIdx.x; i < 160 * 64; i += 256) {
        int c = i >> 6, j = i & 63;
        int l = l0 + j;
        xs[i] = (l < L) ? b2f(xb[c * L + l]) : 0.f;
    }
    __syncthreads();
    int li = threadIdx.x & 63;
    int og = __builtin_amdgcn_readfirstlane(threadIdx.x >> 6);
    int o0 = blockIdx.y * 40 + og * 10;
    float acc[10];
#pragma unroll
    for (int j = 0; j < 10; j++) acc[j] = bias[o0 + j];
    for (int c = 0; c < 160; c++) {
        float xv = xs[(c << 6) + li];
        const float* wr = wt + c * 160 + o0;
#pragma unroll
        for (int j = 0; j < 10; j++) acc[j] += xv * wr[j];
    }
    int l = l0 + li;
    if (l < L) {
        OT* yr = y + ((size_t)b * L + l) * 160 + o0;
#pragma unroll
        for (int j = 0; j < 10; j++) stv(yr + j, acc[j]);
    }
}

// ---------------- mean over d (49) -> Mp_t [b][160][1184] bf16 ----------------
// thread k, 32 p per block; datt column register-cached. grid NB*37, block 192.
#define MP_PITCH 1184
__global__ __launch_bounds__(192) void mean_p_kernel(const float* __restrict__ datt,
                                                     const bf16* __restrict__ patt,
                                                     bf16* __restrict__ MpT) {
    int b = blockIdx.x / 37;
    int p0 = (blockIdx.x % 37) * 32;
    int k = threadIdx.x;
    if (k >= 160) return;
    float dv[49];
#pragma unroll
    for (int d = 0; d < 49; d++) dv[d] = datt[((size_t)b * 49 + d) * 160 + k];
    float s[32];
#pragma unroll
    for (int pi = 0; pi < 32; pi++) {
        int p = p0 + pi;
        float acc = 0.f;
        if (p < 1179) {
            float pv = b2f(patt[((size_t)b * 1179 + p) * 160 + k]);
#pragma unroll
            for (int d = 0; d < 49; d++) acc += fmaxf(dv[d] + pv, 0.f);
        }
        s[pi] = acc * (1.f / 49.f);
    }
    unsigned short* row = (unsigned short*)MpT + ((size_t)b * 160 + k) * MP_PITCH + p0;
#pragma unroll
    for (int g = 0; g < 8; g++) {
        ushort4 u;
        u.x = f2bu(s[g * 4 + 0]); u.y = f2bu(s[g * 4 + 1]);
        u.z = f2bu(s[g * 4 + 2]); u.w = f2bu(s[g * 4 + 3]);
        *(ushort4*)(row + g * 4) = u;
    }
}

// ---------------- mean over p (1179) partial -> atomicAdd into Md f32 ----------------
// grid (NB, 12), block 192. chunk = 99.
__global__ __launch_bounds__(192) void mean_d_partial(const float* __restrict__ datt,
                                                      const bf16* __restrict__ patt,
                                                      float* __restrict__ Md) {
    int b = blockIdx.x;
    int ps = blockIdx.y;
    int k = threadIdx.x;
    if (k >= 160) return;
    int p0 = ps * 99, p1 = min(p0 + 99, 1179);
    float dv[49], acc[49];
#pragma unroll
    for (int d = 0; d < 49; d++) {
        dv[d] = datt[((size_t)b * 49 + d) * 160 + k];
        acc[d] = 0.f;
    }
    for (int p = p0; p < p1; p++) {
        float pv = b2f(patt[((size_t)b * 1179 + p) * 160 + k]);
#pragma unroll
        for (int d = 0; d < 49; d++) acc[d] += fmaxf(dv[d] + pv, 0.f);
    }
#pragma unroll
    for (int d = 0; d < 49; d++)
        atomicAdd(Md + ((size_t)b * 49 + d) * 160 + k, acc[d]);
}

// Md f32 [b][49][160] -> Md_t bf16 [b][160][56] with 1/1179 scale
#define MD_PITCH 56
__global__ void md_transpose(const float* __restrict__ Md, bf16* __restrict__ MdT) {
    int b = blockIdx.x;
    for (int i = threadIdx.x; i < 160 * 64; i += 256) {
        int k = i >> 6, d = i & 63;
        if (d < 49)
            MdT[((size_t)b * 160 + k) * MD_PITCH + d] =
                __float2bfloat16(Md[((size_t)b * 49 + d) * 160 + k] * (1.f / 1179.f));
    }
}

// ---------------- sigmoid(M @ attW^T + attb) * conv, fused max-pool ----------------
// grid (NB*tiles, 4), block 256. Shuffle-reduce max over 64 positions, then
// one atomicMax per (o) per wave into pair (values >= 0, pair zero-initialized).
__global__ __launch_bounds__(256) void att_sig_max(const bf16* __restrict__ Mt, int LP, int L,
                                                   int tiles, const float* __restrict__ wattT,
                                                   const float* __restrict__ attbF,
                                                   const bf16* __restrict__ conv,
                                                   float* __restrict__ pair, int off) {
    __shared__ float sM[160 * 64];
    int b = blockIdx.x / tiles;
    int p0 = (blockIdx.x % tiles) << 6;
    const bf16* mb = Mt + (size_t)b * 160 * LP;
    for (int i = threadIdx.x; i < 160 * 64; i += 256) {
        int c = i >> 6, j = i & 63;
        int p = p0 + j;
        sM[i] = (p < L) ? b2f(mb[(size_t)c * LP + p]) : 0.f;
    }
    __syncthreads();
    int li = threadIdx.x & 63;
    int sg = __builtin_amdgcn_readfirstlane(threadIdx.x >> 6);
    int o0 = blockIdx.y * 40 + sg * 10;
    float acc[10];
#pragma unroll
    for (int j = 0; j < 10; j++) acc[j] = attbF[o0 + j];
    for (int c = 0; c < 160; c++) {
        float xv = sM[(c << 6) + li];
        const float* wr = wattT + c * 160 + o0;
#pragma unroll
        for (int j = 0; j < 10; j++) acc[j] += xv * wr[j];
    }
    int p = p0 + li;
    float vmax[10];
#pragma unroll
    for (int j = 0; j < 10; j++) {
        float sig = 1.f / (1.f + __expf(-acc[j]));
        float v = 0.f;
        if (p < L) v = b2f(conv[((size_t)b * 160 + o0 + j) * L + p]) * (0.5f + sig);
        vmax[j] = v;
    }
#pragma unroll
    for (int m = 1; m < 64; m <<= 1) {
#pragma unroll
        for (int j = 0; j < 10; j++)
            vmax[j] = fmaxf(vmax[j], __shfl_xor(vmax[j], m, 64));
    }
    if (li == 0) {
#pragma unroll
        for (int j = 0; j < 10; j++)
            atomicMax((unsigned int*)(pair + b * 320 + off + o0 + j),
                      __float_as_uint(vmax[j]));
    }
}

// ---------------- MLP head (vectorized weight loads) ----------------
__global__ void lin_leaky(const float* __restrict__ in, const void* __restrict__ W,
                          const float* __restrict__ bias, float* __restrict__ out,
                          int IN, int OUT, const int* __restrict__ flagp) {
    int idx = blockIdx.x * 256 + threadIdx.x;
    if (idx >= NB * OUT) return;
    int b = idx / OUT, j = idx - b * OUT;
    const float4* ir4 = (const float4*)(in + (size_t)b * IN);
    float acc = bias[j];
    if (*flagp) {
        const ushort4* wr4 = (const ushort4*)((const unsigned short*)W + (size_t)j * IN);
        for (int i = 0; i < IN / 4; i++) {
            ushort4 u = wr4[i];
            float4 x = ir4[i];
            acc += x.x * u16bf(u.x) + x.y * u16bf(u.y) + x.z * u16bf(u.z) + x.w * u16bf(u.w);
        }
    } else {
        const float4* wr4 = (const float4*)((const float*)W + (size_t)j * IN);
        for (int i = 0; i < IN / 4; i++) {
            float4 w = wr4[i];
            float4 x = ir4[i];
            acc += x.x * w.x + x.y * w.y + x.z * w.z + x.w * w.w;
        }
    }
    out[idx] = acc > 0.f ? acc : 0.01f * acc;
}

__global__ void out_layer(const float* __restrict__ h, const void* __restrict__ W,
                          const float* __restrict__ biasF, void* __restrict__ out,
                          const int* __restrict__ flagp) {
    int idx = threadIdx.x;
    if (idx >= 32) return;
    int b = idx >> 1, o = idx & 1;
    float acc = biasF[o];
    const float* ir = h + b * 512;
    if (*flagp) {
        const bf16* wr = (const bf16*)W + o * 512;
        for (int i = 0; i < 512; i++) acc += ir[i] * b2f(wr[i]);
        ((bf16*)out)[idx] = __float2bfloat16(acc);
    } else {
        const float* wr = (const float*)W + o * 512;
        for (int i = 0; i < 512; i++) acc += ir[i] * wr[i];
        ((float*)out)[idx] = acc;
    }
}

extern "C" void kernel_launch(void* const* d_in, const int* in_sizes, int n_in,
                              void* d_out, int out_size, void* d_ws, size_t ws_size,
                              hipStream_t stream) {
    const int* drug_tok = (const int*)d_in[0];
    const int* prot_tok = (const int*)d_in[1];
    const void* drug_emb = d_in[2];
    const void* prot_emb = d_in[3];
    const void* dW1 = d_in[4];  const void* db1 = d_in[5];
    const void* dW2 = d_in[6];  const void* db2 = d_in[7];
    const void* dW3 = d_in[8];  const void* db3 = d_in[9];
    const void* pW1 = d_in[10]; const void* pb1 = d_in[11];
    const void* pW2 = d_in[12]; const void* pb2 = d_in[13];
    const void* pW3 = d_in[14]; const void* pb3 = d_in[15];
    const void* dattW = d_in[16]; const void* dattb = d_in[17];
    const void* pattW = d_in[18]; const void* pattb = d_in[19];
    const void* attW  = d_in[20]; const void* attb  = d_in[21];
    const void* fc1W = d_in[22]; const void* fc1b = d_in[23];
    const void* fc2W = d_in[24]; const void* fc2b = d_in[25];
    const void* fc3W = d_in[26]; const void* fc3b = d_in[27];
    const void* outW = d_in[28]; const void* outb = d_in[29];

    char* base = (char*)d_ws;
    size_t cur = 0;
    auto alloc = [&](size_t bytes) -> char* {
        char* p = base + cur;
        cur = (cur + bytes + 255) & ~(size_t)255;
        return p;
    };
    int*   flag  = (int*)alloc(256);
    float* embDF = (float*)alloc(65 * 64 * 4);
    float* embPF = (float*)alloc(26 * 64 * 4);
    float* dW1t = (float*)alloc(10240 * 4);
    float* dW2t = (float*)alloc(19200 * 4);
    float* dW3t = (float*)alloc(102400 * 4);
    float* pW1t = (float*)alloc(10240 * 4);
    float* pW2t = (float*)alloc(25600 * 4);
    float* pW3t = (float*)alloc(153600 * 4);
    float* db1f = (float*)alloc(40 * 4);
    float* db2f = (float*)alloc(80 * 4);
    float* db3f = (float*)alloc(160 * 4);
    float* pb1f = (float*)alloc(40 * 4);
    float* pb2f = (float*)alloc(80 * 4);
    float* pb3f = (float*)alloc(160 * 4);
    float* dattbF = (float*)alloc(160 * 4);
    float* pattbF = (float*)alloc(160 * 4);
    float* attbF  = (float*)alloc(160 * 4);
    float* fc1bF = (float*)alloc(1024 * 4);
    float* fc2bF = (float*)alloc(1024 * 4);
    float* fc3bF = (float*)alloc(512 * 4);
    float* outbF = (float*)alloc(2 * 4);
    float* dattT = (float*)alloc(25600 * 4);
    float* pattT = (float*)alloc(25600 * 4);
    float* wattT = (float*)alloc(25600 * 4);
    bf16* d1  = (bf16*)alloc((size_t)NB * 40 * 61 * 2);
    bf16* d2  = (bf16*)alloc((size_t)NB * 80 * 56 * 2);
    bf16* dcB = (bf16*)alloc((size_t)NB * 160 * 49 * 2);
    bf16* p1  = (bf16*)alloc((size_t)NB * 40 * 1197 * 2);
    bf16* p2  = (bf16*)alloc((size_t)NB * 80 * 1190 * 2);
    bf16* pcB = (bf16*)alloc((size_t)NB * 160 * 1179 * 2);
    float* datt  = (float*)alloc((size_t)NB * 49 * 160 * 4);
    bf16* pattB = (bf16*)alloc((size_t)NB * 1179 * 160 * 2);
    float* Md   = (float*)alloc((size_t)NB * 49 * 160 * 4);
    bf16* MdT  = (bf16*)alloc((size_t)NB * 160 * MD_PITCH * 2);
    bf16* MpT  = (bf16*)alloc((size_t)NB * 160 * MP_PITCH * 2);
    float* pair = (float*)alloc(NB * 320 * 4);
    float* h1 = (float*)alloc(NB * 1024 * 4);
    float* h2 = (float*)alloc(NB * 1024 * 4);
    float* h3 = (float*)alloc(NB * 512 * 4);

    // 1) dtype sniff
    sniff_kernel<<<1, 256, 0, stream>>>((const unsigned short*)fc2W, flag);

    // 2) parameter conversion
    CvtJob job;
    int si = 0;
    auto add = [&](const void* s, float* d, int n) { job.src[si] = s; job.dst[si] = d; job.n[si] = n; si++; };
    add(db1, db1f, 40); add(db2, db2f, 80); add(db3, db3f, 160);
    add(pb1, pb1f, 40); add(pb2, pb2f, 80); add(pb3, pb3f, 160);
    add(dattb, dattbF, 160); add(pattb, pattbF, 160); add(attb, attbF, 160);
    add(fc1b, fc1bF, 1024); add(fc2b, fc2bF, 1024); add(fc3b, fc3bF, 512);
    add(outb, outbF, 2);
    add(drug_emb, embDF, 65 * 64); add(prot_emb, embPF, 26 * 64);
    megacvt<<<dim3(17, NSEG), 256, 0, stream>>>(job, flag);
    cvt_wT<<<40, 256, 0, stream>>>(dW1, dW1t, 40, 256, flag);
    cvt_wT<<<75, 256, 0, stream>>>(dW2, dW2t, 80, 240, flag);
    cvt_wT<<<400, 256, 0, stream>>>(dW3, dW3t, 160, 640, flag);
    cvt_wT<<<40, 256, 0, stream>>>(pW1, pW1t, 40, 256, flag);
    cvt_wT<<<100, 256, 0, stream>>>(pW2, pW2t, 80, 320, flag);
    cvt_wT<<<600, 256, 0, stream>>>(pW3, pW3t, 160, 960, flag);
    cvt160t<<<dim3(100, 3), 256, 0, stream>>>(dattW, pattW, attW, dattT, pattT, wattT, flag);
    zero_init<<<(NB * 49 * 160 + 255) / 256, 256, 0, stream>>>(pair, Md);

    // 3) CNN stacks
    conv1_embed<<<dim3(NB * 1, 1), 256, 0, stream>>>(drug_tok, embDF, dW1t, db1f, d1, 64, 61, 1);
    conv1_embed<<<dim3(NB * 10, 1), 256, 0, stream>>>(prot_tok, embPF, pW1t, pb1f, p1, 1200, 1197, 10);
    conv_v2<40, 6, 10><<<dim3(NB * 1, 2), 256, 0, stream>>>(d1, dW2t, db2f, d2, 61, 56, 80, 1);
    conv_v2<40, 8, 10><<<dim3(NB * 10, 2), 256, 0, stream>>>(p1, pW2t, pb2f, p2, 1197, 1190, 80, 10);
    conv_v2<80, 8, 10><<<dim3(NB * 1, 4), 256, 0, stream>>>(d2, dW3t, db3f, dcB, 56, 49, 160, 1);
    conv_v2<80, 12, 10><<<dim3(NB * 10, 4), 256, 0, stream>>>(p2, pW3t, pb3f, pcB, 1190, 1179, 160, 10);

    // 4) attention projections
    att_proj<float><<<dim3(NB * 1, 4), 256, 0, stream>>>(dcB, dattT, dattbF, datt, 49);
    att_proj<bf16><<<dim3(NB * 19, 4), 256, 0, stream>>>(pcB, pattT, pattbF, pattB, 1179);

    // 5) pairwise relu-means
    mean_p_kernel<<<NB * 37, 192, 0, stream>>>(datt, pattB, MpT);
    mean_d_partial<<<dim3(NB, 12), 192, 0, stream>>>(datt, pattB, Md);
    md_transpose<<<NB, 256, 0, stream>>>(Md, MdT);

    // 6) fused attW-matmul + sigmoid + scale + maxpool
    att_sig_max<<<dim3(NB * 1, 4), 256, 0, stream>>>(MdT, MD_PITCH, 49, 1, wattT, attbF, dcB, pair, 0);
    att_sig_max<<<dim3(NB * 19, 4), 256, 0, stream>>>(MpT, MP_PITCH, 1179, 19, wattT, attbF, pcB, pair, 160);

    // 7) MLP head
    lin_leaky<<<(NB * 1024 + 255) / 256, 256, 0, stream>>>(pair, fc1W, fc1bF, h1, 320, 1024, flag);
    lin_leaky<<<(NB * 1024 + 255) / 256, 256, 0, stream>>>(h1, fc2W, fc2bF, h2, 1024, 1024, flag);
    lin_leaky<<<(NB * 512 + 255) / 256, 256, 0, stream>>>(h2, fc3W, fc3bF, h3, 1024, 512, flag);
    out_layer<<<1, 64, 0, stream>>>(h3, outW, outbF, d_out, flag);
}